// Round 3
// baseline (866.831 us; speedup 1.0000x reference)
//
#include <hip/hip_runtime.h>
#include <hip/hip_bf16.h>
#include <math.h>

typedef __attribute__((ext_vector_type(8))) short bf16x8;
typedef __attribute__((ext_vector_type(4))) float f32x4;
typedef __hip_bfloat16 bf16;

#define MFMA16(a, b, c) __builtin_amdgcn_mfma_f32_16x16x32_bf16((a), (b), (c), 0, 0, 0)

static __device__ inline short f2bf(float f) {
    bf16 h = __float2bfloat16(f);
    return *reinterpret_cast<short*>(&h);
}

// Tiled transpose + cast: dst[n][k] = bf16(src[k][n]). K, N multiples of 32.
__global__ __launch_bounds__(256) void transpose_cast(const float* __restrict__ src,
                                                      bf16* __restrict__ dst, int K, int N) {
    __shared__ float t[32][33];
    int n0 = blockIdx.x * 32, k0 = blockIdx.y * 32;
    int tx = threadIdx.x & 31, ty = threadIdx.x >> 5;
    #pragma unroll
    for (int j = 0; j < 4; j++)
        t[ty + 8 * j][tx] = src[(size_t)(k0 + ty + 8 * j) * N + n0 + tx];
    __syncthreads();
    #pragma unroll
    for (int j = 0; j < 4; j++)
        dst[(size_t)(n0 + ty + 8 * j) * K + k0 + tx] = __float2bfloat16(t[tx][ty + 8 * j]);
}

union Pack4 { bf16 h[4]; uint2 v; };

// One block per row (1024 f32). rows [0,16384): query -> qn + qraw ; rows [16384,32768): support -> sn
__global__ __launch_bounds__(256) void ln_kernel(
    const float* __restrict__ qf, const float* __restrict__ sf,
    const float* __restrict__ qw, const float* __restrict__ qb,
    const float* __restrict__ sw, const float* __restrict__ sb,
    bf16* __restrict__ qn, bf16* __restrict__ sn, bf16* __restrict__ qraw) {
    int row = blockIdx.x;
    bool isQ = row < 16384;
    int r = isQ ? row : row - 16384;
    const float* src = (isQ ? qf : sf) + (size_t)r * 1024;
    const float* w = isQ ? qw : sw;
    const float* b = isQ ? qb : sb;
    int t = threadIdx.x;
    float4 x = reinterpret_cast<const float4*>(src)[t];
    float s = x.x + x.y + x.z + x.w;
    float ss = x.x * x.x + x.y * x.y + x.z * x.z + x.w * x.w;
    #pragma unroll
    for (int m = 1; m < 64; m <<= 1) { s += __shfl_xor(s, m); ss += __shfl_xor(ss, m); }
    __shared__ float rs_[4], rss_[4];
    int wave = t >> 6;
    if ((t & 63) == 0) { rs_[wave] = s; rss_[wave] = ss; }
    __syncthreads();
    s = rs_[0] + rs_[1] + rs_[2] + rs_[3];
    ss = rss_[0] + rss_[1] + rss_[2] + rss_[3];
    float mu = s * (1.0f / 1024.0f);
    float var = ss * (1.0f / 1024.0f) - mu * mu;
    float rstd = rsqrtf(var + 1e-5f);
    float4 wv = reinterpret_cast<const float4*>(w)[t];
    float4 bv = reinterpret_cast<const float4*>(b)[t];
    Pack4 o;
    o.h[0] = __float2bfloat16((x.x - mu) * rstd * wv.x + bv.x);
    o.h[1] = __float2bfloat16((x.y - mu) * rstd * wv.y + bv.y);
    o.h[2] = __float2bfloat16((x.z - mu) * rstd * wv.z + bv.z);
    o.h[3] = __float2bfloat16((x.w - mu) * rstd * wv.w + bv.w);
    bf16* dst = (isQ ? qn : sn) + (size_t)r * 1024 + t * 4;
    *reinterpret_cast<uint2*>(dst) = o.v;
    if (isQ) {
        Pack4 o2;
        o2.h[0] = __float2bfloat16(x.x);
        o2.h[1] = __float2bfloat16(x.y);
        o2.h[2] = __float2bfloat16(x.z);
        o2.h[3] = __float2bfloat16(x.w);
        bf16* d2 = qraw + (size_t)r * 1024 + t * 4;
        *reinterpret_cast<uint2*>(d2) = o2.v;
    }
}

// C = A(MxK) @ Bt(NxK)^T, bf16, K contiguous. BM x 128 tile, BK=64, 4 waves (2Mx2N).
// MODE 0: out bf16 per-head [b][h][n][d]                      (Q projection)
// MODE 4: gN<256 -> Kh [b][h][n][d]; gN>=256 -> Vt [b][h][d][n]  (merged K,V)
// MODE 2: out bf16 = sigmoid(acc + bias), plain [M][N]           (gate)
// MODE 3: out f32 = resid + gate * (acc + bias), plain [M][N]    (final)
template <int MODE, int BM>
__global__ __launch_bounds__(256) void gemm_bf16(
    const bf16* __restrict__ A, const bf16* __restrict__ Bt,
    const float* __restrict__ bias, const float* __restrict__ bias2,
    void* __restrict__ outp, void* __restrict__ outp2,
    const bf16* __restrict__ gate, const float* __restrict__ resid,
    int M, int N, int Kd) {
    constexpr int MF = BM / 32;  // M-frags per wave (wave covers BM/2 rows)
    __shared__ alignas(16) short lsA[BM * 72];   // pad 64->72: 2-way conflicts only
    __shared__ alignas(16) short lsB[128 * 72];
    int tid = threadIdx.x;
    int m0 = blockIdx.x * BM, n0 = blockIdx.y * 128;
    int wave = tid >> 6, lane = tid & 63;
    int wr = wave >> 1, wc = wave & 1;
    int lrow = lane & 15, kgrp = lane >> 4;
    f32x4 acc[MF][4];
    #pragma unroll
    for (int i = 0; i < MF; i++)
        #pragma unroll
        for (int j = 0; j < 4; j++) acc[i][j] = (f32x4){0.f, 0.f, 0.f, 0.f};
    int nkt = Kd >> 6;
    for (int kt = 0; kt < nkt; kt++) {
        int k0 = kt * 64;
        constexpr int CA = BM * 8 / 256;
        #pragma unroll
        for (int i = 0; i < CA; i++) {
            int ci = tid + i * 256, row = ci >> 3, cc = ci & 7;
            *reinterpret_cast<bf16x8*>(lsA + row * 72 + cc * 8) =
                *reinterpret_cast<const bf16x8*>(A + (size_t)(m0 + row) * Kd + k0 + cc * 8);
        }
        #pragma unroll
        for (int i = 0; i < 4; i++) {
            int ci = tid + i * 256, row = ci >> 3, cc = ci & 7;
            *reinterpret_cast<bf16x8*>(lsB + row * 72 + cc * 8) =
                *reinterpret_cast<const bf16x8*>(Bt + (size_t)(n0 + row) * Kd + k0 + cc * 8);
        }
        __syncthreads();
        #pragma unroll
        for (int kc = 0; kc < 2; kc++) {
            bf16x8 aF[MF], bF[4];
            #pragma unroll
            for (int mf = 0; mf < MF; mf++)
                aF[mf] = *reinterpret_cast<const bf16x8*>(
                    lsA + (wr * (BM / 2) + mf * 16 + lrow) * 72 + kc * 32 + kgrp * 8);
            #pragma unroll
            for (int nf = 0; nf < 4; nf++)
                bF[nf] = *reinterpret_cast<const bf16x8*>(
                    lsB + (wc * 64 + nf * 16 + lrow) * 72 + kc * 32 + kgrp * 8);
            #pragma unroll
            for (int mf = 0; mf < MF; mf++)
                #pragma unroll
                for (int nf = 0; nf < 4; nf++)
                    acc[mf][nf] = MFMA16(aF[mf], bF[nf], acc[mf][nf]);
        }
        __syncthreads();
    }
    #pragma unroll
    for (int mf = 0; mf < MF; mf++) {
        #pragma unroll
        for (int nf = 0; nf < 4; nf++) {
            #pragma unroll
            for (int r = 0; r < 4; r++) {
                int gM = m0 + wr * (BM / 2) + mf * 16 + kgrp * 4 + r;
                int gN = n0 + wc * 64 + nf * 16 + lrow;
                if (MODE == 0) {
                    float v = acc[mf][nf][r] + bias[gN];
                    int b = gM >> 10, n = gM & 1023, h = gN >> 6, d = gN & 63;
                    ((bf16*)outp)[(((size_t)(b * 4 + h)) << 16) + (n << 6) + d] = __float2bfloat16(v);
                } else if (MODE == 4) {
                    int b = gM >> 10, n = gM & 1023;
                    if (gN < 256) {
                        float v = acc[mf][nf][r] + bias[gN];
                        int h = gN >> 6, d = gN & 63;
                        ((bf16*)outp)[(((size_t)(b * 4 + h)) << 16) + (n << 6) + d] = __float2bfloat16(v);
                    } else {
                        float v = acc[mf][nf][r] + bias2[gN - 256];
                        int h = (gN - 256) >> 6, d = gN & 63;
                        ((bf16*)outp2)[(((size_t)(b * 4 + h)) << 16) + (d << 10) + n] = __float2bfloat16(v);
                    }
                } else if (MODE == 2) {
                    float v = acc[mf][nf][r] + bias[gN];
                    float g = 1.0f / (1.0f + __expf(-v));
                    ((bf16*)outp)[(size_t)gM * N + gN] = __float2bfloat16(g);
                } else {
                    float v = acc[mf][nf][r] + bias[gN];
                    float g = __bfloat162float(gate[(size_t)gM * N + gN]);
                    float q = resid[(size_t)gM * N + gN];
                    ((float*)outp)[(size_t)gM * N + gN] = q + g * v;
                }
            }
        }
    }
}

// Fused attention per (b,h). 3-pass, swapped-QK^T so softmax reductions are lane-local:
//  pass1: mfma(K,Q) -> lane holds scores for q=lane&15, keys kgrp*4+r (+16kt); row max = fmax chain + 2 shfl.
//  pass2: recompute, e=exp(s-m); ssum (lane-local + 2 shfl); unnormalized P@V via LDS transpose (dbuf).
//  pass3: recompute in ORIGINAL orientation (coalesced store), write p=exp(s-m)*inv.
// grid = 64 heads * 16 q-tiles; block = 4 waves, each wave owns 16 q rows.
__global__ __launch_bounds__(256) void attn_kernel(
    const bf16* __restrict__ Qh, const bf16* __restrict__ Kh, const bf16* __restrict__ Vt,
    const float* __restrict__ mask, float* __restrict__ attn_out, bf16* __restrict__ ctx) {
    __shared__ alignas(16) short P2[4][2][16][40];  // per-wave dbuf P tile, stride 40: 2-way only
    __shared__ float ms_[4][16], is_[4][16];
    int bh = blockIdx.x >> 4, qt = blockIdx.x & 15;
    int b = bh >> 2, h = bh & 3;
    int wave = threadIdx.x >> 6, lane = threadIdx.x & 63;
    int lrow = lane & 15, kgrp = lane >> 4;
    const bf16* Qb = Qh + ((size_t)bh << 16);
    const bf16* Kb = Kh + ((size_t)bh << 16);
    const bf16* Vb = Vt + ((size_t)bh << 16);
    const float* mb = mask + b * 1024;
    int q0 = qt * 64 + wave * 16;
    bf16x8 qf0 = *reinterpret_cast<const bf16x8*>(Qb + (q0 + lrow) * 64 + kgrp * 8);
    bf16x8 qf1 = *reinterpret_cast<const bf16x8*>(Qb + (q0 + lrow) * 64 + 32 + kgrp * 8);

    // ---- pass 1: row max ----
    float mx = -1e30f;
    for (int kt = 0; kt < 64; kt++) {
        bf16x8 kf0 = *reinterpret_cast<const bf16x8*>(Kb + (kt * 16 + lrow) * 64 + kgrp * 8);
        bf16x8 kf1 = *reinterpret_cast<const bf16x8*>(Kb + (kt * 16 + lrow) * 64 + 32 + kgrp * 8);
        f32x4 acc = (f32x4){0.f, 0.f, 0.f, 0.f};
        acc = MFMA16(kf0, qf0, acc);
        acc = MFMA16(kf1, qf1, acc);
        float4 mv = *reinterpret_cast<const float4*>(mb + kt * 16 + kgrp * 4);
        float s0 = fmaxf(acc[0] * 0.125f + 5.f * mv.x, acc[1] * 0.125f + 5.f * mv.y);
        float s1 = fmaxf(acc[2] * 0.125f + 5.f * mv.z, acc[3] * 0.125f + 5.f * mv.w);
        mx = fmaxf(mx, fmaxf(s0, s1));
    }
    mx = fmaxf(mx, __shfl_xor(mx, 16));
    mx = fmaxf(mx, __shfl_xor(mx, 32));

    // ---- pass 2: sum-exp + unnormalized P@V ----
    float ssum = 0.f;
    f32x4 cacc[4];
    #pragma unroll
    for (int nf = 0; nf < 4; nf++) cacc[nf] = (f32x4){0.f, 0.f, 0.f, 0.f};
    for (int kt = 0; kt < 64; kt++) {
        bf16x8 kf0 = *reinterpret_cast<const bf16x8*>(Kb + (kt * 16 + lrow) * 64 + kgrp * 8);
        bf16x8 kf1 = *reinterpret_cast<const bf16x8*>(Kb + (kt * 16 + lrow) * 64 + 32 + kgrp * 8);
        f32x4 acc = (f32x4){0.f, 0.f, 0.f, 0.f};
        acc = MFMA16(kf0, qf0, acc);
        acc = MFMA16(kf1, qf1, acc);
        float4 mv = *reinterpret_cast<const float4*>(mb + kt * 16 + kgrp * 4);
        float e0 = __expf(acc[0] * 0.125f + 5.f * mv.x - mx);
        float e1 = __expf(acc[1] * 0.125f + 5.f * mv.y - mx);
        float e2 = __expf(acc[2] * 0.125f + 5.f * mv.z - mx);
        float e3 = __expf(acc[3] * 0.125f + 5.f * mv.w - mx);
        ssum += (e0 + e1) + (e2 + e3);
        short4 pk;
        pk.x = f2bf(e0); pk.y = f2bf(e1); pk.z = f2bf(e2); pk.w = f2bf(e3);
        *reinterpret_cast<short4*>(&P2[wave][(kt >> 1) & 1][lrow][(kt & 1) * 16 + kgrp * 4]) = pk;
        if (kt & 1) {
            __syncthreads();  // intra-wave LDS fence (regions are per-wave private)
            bf16x8 aP = *reinterpret_cast<const bf16x8*>(&P2[wave][(kt >> 1) & 1][lrow][kgrp * 8]);
            int k2 = (kt >> 1) * 32;
            #pragma unroll
            for (int nf = 0; nf < 4; nf++) {
                bf16x8 bV = *reinterpret_cast<const bf16x8*>(Vb + (nf * 16 + lrow) * 1024 + k2 + kgrp * 8);
                cacc[nf] = MFMA16(aP, bV, cacc[nf]);
            }
        }
    }
    ssum += __shfl_xor(ssum, 16);
    ssum += __shfl_xor(ssum, 32);
    float inv = 1.0f / ssum;
    if (kgrp == 0) { ms_[wave][lrow] = mx; is_[wave][lrow] = inv; }
    __syncthreads();
    float m4[4], i4[4];
    #pragma unroll
    for (int r = 0; r < 4; r++) { m4[r] = ms_[wave][kgrp * 4 + r]; i4[r] = is_[wave][kgrp * 4 + r]; }
    // ctx store (cacc rows are q = kgrp*4+r -> scale by i4[r])
    #pragma unroll
    for (int nf = 0; nf < 4; nf++) {
        #pragma unroll
        for (int r = 0; r < 4; r++) {
            int qrow = q0 + kgrp * 4 + r;
            ctx[((size_t)(b * 1024 + qrow)) * 256 + h * 64 + nf * 16 + lrow] =
                __float2bfloat16(cacc[nf][r] * i4[r]);
        }
    }
    // ---- pass 3: attn store, original orientation (coalesced 64B segments) ----
    float* aout = attn_out + ((size_t)bh << 20) + (size_t)q0 * 1024;
    for (int kt = 0; kt < 64; kt++) {
        bf16x8 kf0 = *reinterpret_cast<const bf16x8*>(Kb + (kt * 16 + lrow) * 64 + kgrp * 8);
        bf16x8 kf1 = *reinterpret_cast<const bf16x8*>(Kb + (kt * 16 + lrow) * 64 + 32 + kgrp * 8);
        f32x4 acc = (f32x4){0.f, 0.f, 0.f, 0.f};
        acc = MFMA16(qf0, kf0, acc);
        acc = MFMA16(qf1, kf1, acc);
        float mv = 5.f * mb[kt * 16 + lrow];
        #pragma unroll
        for (int r = 0; r < 4; r++) {
            float p = __expf(acc[r] * 0.125f + mv - m4[r]) * i4[r];
            aout[(kgrp * 4 + r) * 1024 + kt * 16 + lrow] = p;
        }
    }
}

extern "C" void kernel_launch(void* const* d_in, const int* in_sizes, int n_in,
                              void* d_out, int out_size, void* d_ws, size_t ws_size,
                              hipStream_t stream) {
    const float* qf = (const float*)d_in[0];
    const float* sf = (const float*)d_in[1];
    const float* mask = (const float*)d_in[2];
    const float* lnqw = (const float*)d_in[3];
    const float* lnqb = (const float*)d_in[4];
    const float* lnsw = (const float*)d_in[5];
    const float* lnsb = (const float*)d_in[6];
    const float* Wq = (const float*)d_in[7];
    const float* bq = (const float*)d_in[8];
    const float* Wk = (const float*)d_in[9];
    const float* bk = (const float*)d_in[10];
    const float* Wv = (const float*)d_in[11];
    const float* bv = (const float*)d_in[12];
    const float* Wo = (const float*)d_in[13];
    const float* bo = (const float*)d_in[14];
    const float* Wg = (const float*)d_in[15];
    const float* bg = (const float*)d_in[16];

    char* ws = (char*)d_ws;
    const size_t MB = 1024 * 1024;
    bf16* wqt  = (bf16*)(ws + 0);                 // 256x1024
    bf16* wkt  = (bf16*)(ws + 512 * 1024);        // 256x1024 } contiguous 512x1024 for merged KV
    bf16* wvt  = (bf16*)(ws + 1024 * 1024);       // 256x1024 }
    bf16* wot  = (bf16*)(ws + 1536 * 1024);       // 1024x256
    bf16* wgt  = (bf16*)(ws + 2 * MB);            // 1024x1024
    bf16* qn   = (bf16*)(ws + 4 * MB);            // 16384x1024; aliased by gate later
    bf16* sn   = (bf16*)(ws + 36 * MB);           // 16384x1024; aliased by ctx later
    bf16* qraw = (bf16*)(ws + 68 * MB);           // 16384x1024
    bf16* Qh   = (bf16*)(ws + 100 * MB);          // [64][1024][64]
    bf16* Kh   = (bf16*)(ws + 108 * MB);          // [64][1024][64]
    bf16* Vt   = (bf16*)(ws + 116 * MB);          // [64][64][1024]
    bf16* gate = qn;   // qn dead after Q projection
    bf16* ctx  = sn;   // sn dead after K,V projection

    float* enh = (float*)d_out;
    float* attn = enh + (size_t)16 * 1024 * 1024;

    // 1. weight transpose + bf16 cast (tiled, coalesced)
    transpose_cast<<<dim3(8, 32), 256, 0, stream>>>(Wq, wqt, 1024, 256);
    transpose_cast<<<dim3(8, 32), 256, 0, stream>>>(Wk, wkt, 1024, 256);
    transpose_cast<<<dim3(8, 32), 256, 0, stream>>>(Wv, wvt, 1024, 256);
    transpose_cast<<<dim3(32, 8), 256, 0, stream>>>(Wo, wot, 256, 1024);
    transpose_cast<<<dim3(32, 32), 256, 0, stream>>>(Wg, wgt, 1024, 1024);
    // 2. layernorm + casts
    ln_kernel<<<32768, 256, 0, stream>>>(qf, sf, lnqw, lnqb, lnsw, lnsb, qn, sn, qraw);
    // 3. projections: Q (BM=64, 512 blocks), merged K+V (BM=64, N=512, 1024 blocks)
    gemm_bf16<0, 64><<<dim3(256, 2), 256, 0, stream>>>(qn, wqt, bq, nullptr, Qh, nullptr,
                                                       nullptr, nullptr, 16384, 256, 1024);
    gemm_bf16<4, 64><<<dim3(256, 4), 256, 0, stream>>>(sn, wkt, bk, bv, Kh, Vt,
                                                       nullptr, nullptr, 16384, 512, 1024);
    // 4. attention (writes attn f32 + ctx bf16)
    attn_kernel<<<1024, 256, 0, stream>>>(Qh, Kh, Vt, mask, attn, ctx);
    // 5. gate = sigmoid(qraw @ Wg + bg)
    gemm_bf16<2, 128><<<dim3(128, 8), 256, 0, stream>>>(qraw, wgt, bg, nullptr, gate, nullptr,
                                                        nullptr, nullptr, 16384, 1024, 1024);
    // 6. enhanced = qf + gate * (ctx @ Wo + bo)
    gemm_bf16<3, 128><<<dim3(128, 8), 256, 0, stream>>>(ctx, wot, bo, nullptr, enh, nullptr,
                                                        gate, qf, 16384, 1024, 256);
}